// Round 2
// baseline (358.089 us; speedup 1.0000x reference)
//
#include <hip/hip_runtime.h>

typedef _Float16 half8  __attribute__((ext_vector_type(8)));
typedef __fp16   fp16x2 __attribute__((ext_vector_type(2)));
typedef float    floatx4 __attribute__((ext_vector_type(4)));

#define LOG2E 1.44269504088896340736f

#define NQ  2048
#define NK  2048
#define DIM 512
#define KT  32
#define BM  64
#define RS  520   // row-major LDS stride (f16 units): 1040B = 16B-aligned, 4-dw bank step
#define TS  40    // transposed LDS stride (f16 units): 80B = 16B-aligned, 20-dw bank step

__device__ __forceinline__ unsigned pk2(float a, float b) {
    fp16x2 h = __builtin_amdgcn_cvt_pkrtz(a, b);
    return __builtin_bit_cast(unsigned, h);
}

__device__ __forceinline__ half8 mk8(unsigned a, unsigned b, unsigned c, unsigned d) {
    union { unsigned u[4]; half8 h; } t;
    t.u[0] = a; t.u[1] = b; t.u[2] = c; t.u[3] = d;
    return t.h;
}

__global__ __launch_bounds__(256, 1)
void attn_fa(const float* __restrict__ Qg, const float* __restrict__ Kg,
             float* __restrict__ Og)
{
    __shared__ __align__(16) _Float16 sKr[KT * RS];    // 33,280 B row-major K tile
    __shared__ __align__(16) _Float16 sKt[DIM * TS];   // 40,960 B transposed K tile

    const int tid  = threadIdx.x;
    const int lane = tid & 63;
    const int wave = tid >> 6;
    const int quad = lane >> 4;
    const int col  = lane & 15;

    const int batch = blockIdx.x & 7;    // XCD swizzle: batch -> XCD, K fits that L2
    const int qtile = blockIdx.x >> 3;

    const int qrow = qtile * BM + wave * 16 + col;

    // ---- Q fragments: B-operand layout Q[q=col][d = dc*32 + quad*8 + j], in regs ----
    const float* qp = Qg + ((size_t)batch * NQ + qrow) * DIM + quad * 8;
    half8 qf[16];
    #pragma unroll
    for (int dc = 0; dc < 16; ++dc) {
        float4 f0 = *(const float4*)(qp + dc * 32);
        float4 f1 = *(const float4*)(qp + dc * 32 + 4);
        qf[dc] = mk8(pk2(f0.x, f0.y), pk2(f0.z, f0.w),
                     pk2(f1.x, f1.y), pk2(f1.z, f1.w));
    }

    // O^T accumulator: tile dt holds O[q=col][d = dt*16 + quad*4 + r]
    floatx4 acc[32];
    #pragma unroll
    for (int i = 0; i < 32; ++i) acc[i] = (floatx4){0.f, 0.f, 0.f, 0.f};

    float m_run = -INFINITY;
    float l_run = 0.f;

    const int kgrp = tid & 7;          // 4-row group of K tile (varies fastest in lane)
    const int dglo = (tid >> 3) & 7;

    for (int kt = 0; kt < NK / KT; ++kt) {
        __syncthreads();
        // ---- stage K tile (fp32 -> fp16), dual copies ----
        #pragma unroll
        for (int i = 0; i < 2; ++i) {
            const int dg = dglo + 8 * ((tid >> 6) + 4 * i);   // 0..63, 8-float column group
            const float* kp = Kg + ((size_t)batch * NK + kt * KT + kgrp * 4) * DIM + dg * 8;
            float rv[4][8];
            #pragma unroll
            for (int kk = 0; kk < 4; ++kk) {
                float4 f0 = *(const float4*)(kp + kk * DIM);
                float4 f1 = *(const float4*)(kp + kk * DIM + 4);
                rv[kk][0] = f0.x; rv[kk][1] = f0.y; rv[kk][2] = f0.z; rv[kk][3] = f0.w;
                rv[kk][4] = f1.x; rv[kk][5] = f1.y; rv[kk][6] = f1.z; rv[kk][7] = f1.w;
            }
            #pragma unroll
            for (int kk = 0; kk < 4; ++kk) {     // row-major copy, b128 writes
                uint4 w;
                w.x = pk2(rv[kk][0], rv[kk][1]);
                w.y = pk2(rv[kk][2], rv[kk][3]);
                w.z = pk2(rv[kk][4], rv[kk][5]);
                w.w = pk2(rv[kk][6], rv[kk][7]);
                *(uint4*)&sKr[(kgrp * 4 + kk) * RS + dg * 8] = w;
            }
            #pragma unroll
            for (int dd = 0; dd < 8; ++dd) {     // transposed copy, b64 writes (4 k per d)
                unsigned lo = pk2(rv[0][dd], rv[1][dd]);
                unsigned hi = pk2(rv[2][dd], rv[3][dd]);
                unsigned long long w = ((unsigned long long)hi << 32) | lo;
                *(unsigned long long*)&sKt[(dg * 8 + dd) * TS + kgrp * 4] = w;
            }
        }
        __syncthreads();

        // ---- S^T = K . Q^T : lane holds S[q=col][k = 16t + quad*4 + r] ----
        floatx4 s0 = {0.f, 0.f, 0.f, 0.f}, s1 = {0.f, 0.f, 0.f, 0.f};
        const _Float16* a0p = &sKr[col * RS + quad * 8];
        const _Float16* a1p = a0p + 16 * RS;
        #pragma unroll
        for (int dc = 0; dc < 16; ++dc) {
            half8 a0 = *(const half8*)(a0p + dc * 32);
            half8 a1 = *(const half8*)(a1p + dc * 32);
            s0 = __builtin_amdgcn_mfma_f32_16x16x32_f16(a0, qf[dc], s0, 0, 0, 0);
            s1 = __builtin_amdgcn_mfma_f32_16x16x32_f16(a1, qf[dc], s1, 0, 0, 0);
        }

        // ---- online softmax (row q = col is lane-local; reduce across quads) ----
        float mloc = fmaxf(fmaxf(fmaxf(s0[0], s0[1]), fmaxf(s0[2], s0[3])),
                           fmaxf(fmaxf(s1[0], s1[1]), fmaxf(s1[2], s1[3])));
        mloc = fmaxf(mloc, __shfl_xor(mloc, 16));
        mloc = fmaxf(mloc, __shfl_xor(mloc, 32));
        const float m_new = fmaxf(m_run, mloc);
        const float alpha = exp2f((m_run - m_new) * LOG2E);
        const float p0 = exp2f((s0[0] - m_new) * LOG2E);
        const float p1 = exp2f((s0[1] - m_new) * LOG2E);
        const float p2 = exp2f((s0[2] - m_new) * LOG2E);
        const float p3 = exp2f((s0[3] - m_new) * LOG2E);
        const float p4 = exp2f((s1[0] - m_new) * LOG2E);
        const float p5 = exp2f((s1[1] - m_new) * LOG2E);
        const float p6 = exp2f((s1[2] - m_new) * LOG2E);
        const float p7 = exp2f((s1[3] - m_new) * LOG2E);
        float sloc = ((p0 + p1) + (p2 + p3)) + ((p4 + p5) + (p6 + p7));
        sloc += __shfl_xor(sloc, 16);
        sloc += __shfl_xor(sloc, 32);
        l_run = l_run * alpha + sloc;
        m_run = m_new;

        #pragma unroll
        for (int i = 0; i < 32; ++i) acc[i] *= alpha;

        // ---- P fragment: B[k = quad*8+j][q = col] via cross-quad shuffles ----
        const unsigned pk00 = pk2(p0, p1);
        const unsigned pk01 = pk2(p2, p3);
        const unsigned pk10 = pk2(p4, p5);
        const unsigned pk11 = pk2(p6, p7);
        const int srcA = col + ((quad & 1) << 5);
        const int srcB = srcA + 16;
        const unsigned a00 = (unsigned)__shfl((int)pk00, srcA);
        const unsigned a01 = (unsigned)__shfl((int)pk01, srcA);
        const unsigned a10 = (unsigned)__shfl((int)pk10, srcA);
        const unsigned a11 = (unsigned)__shfl((int)pk11, srcA);
        const unsigned b00 = (unsigned)__shfl((int)pk00, srcB);
        const unsigned b01 = (unsigned)__shfl((int)pk01, srcB);
        const unsigned b10 = (unsigned)__shfl((int)pk10, srcB);
        const unsigned b11 = (unsigned)__shfl((int)pk11, srcB);
        const bool hi2 = (quad >= 2);
        const half8 pf = mk8(hi2 ? a10 : a00, hi2 ? a11 : a01,
                             hi2 ? b10 : b00, hi2 ? b11 : b01);

        // ---- O^T += K^T . P^T : A-frag from transposed LDS ----
        const _Float16* tp = &sKt[col * TS + quad * 8];
        #pragma unroll
        for (int dt = 0; dt < 32; ++dt) {
            half8 af = *(const half8*)(tp + dt * 16 * TS);
            acc[dt] = __builtin_amdgcn_mfma_f32_16x16x32_f16(af, pf, acc[dt], 0, 0, 0);
        }
    }

    // ---- epilogue: normalize and store (full 64B lines per wave-store) ----
    const float inv = 1.f / l_run;
    float* op = Og + ((size_t)batch * NQ + qrow) * DIM + quad * 4;
    #pragma unroll
    for (int dt = 0; dt < 32; ++dt) {
        floatx4 v = acc[dt] * inv;
        *(floatx4*)(op + dt * 16) = v;
    }
}

extern "C" void kernel_launch(void* const* d_in, const int* in_sizes, int n_in,
                              void* d_out, int out_size, void* d_ws, size_t ws_size,
                              hipStream_t stream) {
    (void)in_sizes; (void)n_in; (void)d_ws; (void)ws_size; (void)out_size;
    const float* Q = (const float*)d_in[0];
    const float* K = (const float*)d_in[1];
    float* O = (float*)d_out;
    dim3 grid(256), block(256);
    hipLaunchKernelGGL(attn_fa, grid, block, 0, stream, Q, K, O);
}

// Round 3
// 343.325 us; speedup vs baseline: 1.0430x; 1.0430x over previous
//
#include <hip/hip_runtime.h>

typedef _Float16 half8  __attribute__((ext_vector_type(8)));
typedef __fp16   fp16x2 __attribute__((ext_vector_type(2)));
typedef float    floatx4 __attribute__((ext_vector_type(4)));

#define LOG2E 1.44269504088896340736f

#define NQ  2048
#define NK  2048
#define DIM 512
#define KT  32
#define BM  64
#define RS  520   // row-major LDS stride (f16): 1040B
#define TS  40    // transposed LDS stride (f16): 80B; k swizzled by (d>>3)&3 in 8-elt units

__device__ __forceinline__ unsigned pk2(float a, float b) {
    fp16x2 h = __builtin_amdgcn_cvt_pkrtz(a, b);
    return __builtin_bit_cast(unsigned, h);
}

__device__ __forceinline__ half8 mk8(unsigned a, unsigned b, unsigned c, unsigned d) {
    union { unsigned u[4]; half8 h; } t;
    t.u[0] = a; t.u[1] = b; t.u[2] = c; t.u[3] = d;
    return t.h;
}

__global__ __launch_bounds__(512, 2)
void attn_fa(const float* __restrict__ Qg, const float* __restrict__ Kg,
             float* __restrict__ Og)
{
    __shared__ __align__(16) _Float16 sKr[KT * RS];      // 33,280 B row-major K tile
    __shared__ __align__(16) _Float16 sKt[DIM * TS];     // 40,960 B transposed (k-swizzled)
    __shared__ __align__(16) float    sSx[8 * 2 * 64 * 4]; // 16,384 B partial-S exchange

    const int tid  = threadIdx.x;
    const int lane = tid & 63;
    const int wave = tid >> 6;      // 0..7
    const int quad = lane >> 4;
    const int col  = lane & 15;
    const int wq   = wave & 3;      // q-strip within 64-row tile
    const int wg   = wave >> 2;     // d-half: 0 -> d[0,256), 1 -> d[256,512)
    const int dbase = wg * 256;

    const int batch = blockIdx.x & 7;    // batch -> XCD: per-batch K resident in one L2
    const int qtile = blockIdx.x >> 3;
    const int qrow  = qtile * BM + wq * 16 + col;

    // ---- Q fragments, this wave's d-half: B-layout Q[q=col][d = dbase+dc*32+quad*8+j] ----
    const float* qp = Qg + ((size_t)batch * NQ + qrow) * DIM + dbase + quad * 8;
    half8 qf[8];
    #pragma unroll
    for (int dc = 0; dc < 8; ++dc) {
        float4 f0 = *(const float4*)(qp + dc * 32);
        float4 f1 = *(const float4*)(qp + dc * 32 + 4);
        qf[dc] = mk8(pk2(f0.x, f0.y), pk2(f0.z, f0.w),
                     pk2(f1.x, f1.y), pk2(f1.z, f1.w));
    }

    // O^T accumulator, d-half: tile dt holds O[q=col][d = dbase + dt*16 + quad*4 + r]
    floatx4 acc[16];
    #pragma unroll
    for (int i = 0; i < 16; ++i) acc[i] = (floatx4){0.f, 0.f, 0.f, 0.f};

    float m_run = -INFINITY;
    float l_run = 0.f;

    const int kgrp = tid & 7;       // 4-row k group
    const int dg   = tid >> 3;      // 0..63, 8-float d group
    const int swz  = (kgrp >> 1) ^ (dg & 3);   // k 8-block swizzle key

    for (int kt = 0; kt < NK / KT; ++kt) {
        __syncthreads();
        // ---- stage K tile (fp32 -> fp16), 512 threads cover it in one pass ----
        {
            const float* kp = Kg + ((size_t)batch * NK + kt * KT + kgrp * 4) * DIM + dg * 8;
            float rv[4][8];
            #pragma unroll
            for (int kk = 0; kk < 4; ++kk) {
                float4 f0 = *(const float4*)(kp + kk * DIM);
                float4 f1 = *(const float4*)(kp + kk * DIM + 4);
                rv[kk][0] = f0.x; rv[kk][1] = f0.y; rv[kk][2] = f0.z; rv[kk][3] = f0.w;
                rv[kk][4] = f1.x; rv[kk][5] = f1.y; rv[kk][6] = f1.z; rv[kk][7] = f1.w;
            }
            #pragma unroll
            for (int kk = 0; kk < 4; ++kk) {     // row-major copy, b128 (conflict-free)
                uint4 w;
                w.x = pk2(rv[kk][0], rv[kk][1]);
                w.y = pk2(rv[kk][2], rv[kk][3]);
                w.z = pk2(rv[kk][4], rv[kk][5]);
                w.w = pk2(rv[kk][6], rv[kk][7]);
                *(uint4*)&sKr[(kgrp * 4 + kk) * RS + dg * 8] = w;
            }
            #pragma unroll
            for (int dd = 0; dd < 8; ++dd) {     // transposed copy, b64, swizzled (2-way)
                unsigned lo = pk2(rv[0][dd], rv[1][dd]);
                unsigned hi = pk2(rv[2][dd], rv[3][dd]);
                unsigned long long w = ((unsigned long long)hi << 32) | lo;
                *(unsigned long long*)&sKt[(dg * 8 + dd) * TS + swz * 8 + (kgrp & 1) * 4] = w;
            }
        }
        __syncthreads();

        // ---- partial S^T over this wave's d-half ----
        floatx4 s0 = {0.f, 0.f, 0.f, 0.f}, s1 = {0.f, 0.f, 0.f, 0.f};
        const _Float16* a0p = &sKr[col * RS + dbase + quad * 8];
        const _Float16* a1p = a0p + 16 * RS;
        #pragma unroll
        for (int dc = 0; dc < 8; ++dc) {
            half8 a0 = *(const half8*)(a0p + dc * 32);
            half8 a1 = *(const half8*)(a1p + dc * 32);
            s0 = __builtin_amdgcn_mfma_f32_16x16x32_f16(a0, qf[dc], s0, 0, 0, 0);
            s1 = __builtin_amdgcn_mfma_f32_16x16x32_f16(a1, qf[dc], s1, 0, 0, 0);
        }

        // ---- cross-wave d-half combine (lane-sequential 16B: conflict-free sweep) ----
        *(floatx4*)&sSx[((wave * 2 + 0) * 64 + lane) * 4] = s0;
        *(floatx4*)&sSx[((wave * 2 + 1) * 64 + lane) * 4] = s1;
        __syncthreads();
        {
            const int pw = wave ^ 4;
            floatx4 t0 = *(const floatx4*)&sSx[((pw * 2 + 0) * 64 + lane) * 4];
            floatx4 t1 = *(const floatx4*)&sSx[((pw * 2 + 1) * 64 + lane) * 4];
            s0 += t0;
            s1 += t1;
        }

        // ---- online softmax (row q = col lane-local; reduce across quads) ----
        float mloc = fmaxf(fmaxf(fmaxf(s0[0], s0[1]), fmaxf(s0[2], s0[3])),
                           fmaxf(fmaxf(s1[0], s1[1]), fmaxf(s1[2], s1[3])));
        mloc = fmaxf(mloc, __shfl_xor(mloc, 16));
        mloc = fmaxf(mloc, __shfl_xor(mloc, 32));
        const float m_new = fmaxf(m_run, mloc);
        const float alpha = exp2f((m_run - m_new) * LOG2E);
        const float p0 = exp2f((s0[0] - m_new) * LOG2E);
        const float p1 = exp2f((s0[1] - m_new) * LOG2E);
        const float p2 = exp2f((s0[2] - m_new) * LOG2E);
        const float p3 = exp2f((s0[3] - m_new) * LOG2E);
        const float p4 = exp2f((s1[0] - m_new) * LOG2E);
        const float p5 = exp2f((s1[1] - m_new) * LOG2E);
        const float p6 = exp2f((s1[2] - m_new) * LOG2E);
        const float p7 = exp2f((s1[3] - m_new) * LOG2E);
        float sloc = ((p0 + p1) + (p2 + p3)) + ((p4 + p5) + (p6 + p7));
        sloc += __shfl_xor(sloc, 16);
        sloc += __shfl_xor(sloc, 32);
        l_run = l_run * alpha + sloc;
        m_run = m_new;

        #pragma unroll
        for (int i = 0; i < 16; ++i) acc[i] *= alpha;

        // ---- P fragment: B[k = quad*8+j][q = col] via cross-quad shuffles ----
        const unsigned pk00 = pk2(p0, p1);
        const unsigned pk01 = pk2(p2, p3);
        const unsigned pk10 = pk2(p4, p5);
        const unsigned pk11 = pk2(p6, p7);
        const int srcA = col + ((quad & 1) << 5);
        const int srcB = srcA + 16;
        const unsigned a00 = (unsigned)__shfl((int)pk00, srcA);
        const unsigned a01 = (unsigned)__shfl((int)pk01, srcA);
        const unsigned a10 = (unsigned)__shfl((int)pk10, srcA);
        const unsigned a11 = (unsigned)__shfl((int)pk11, srcA);
        const unsigned b00 = (unsigned)__shfl((int)pk00, srcB);
        const unsigned b01 = (unsigned)__shfl((int)pk01, srcB);
        const unsigned b10 = (unsigned)__shfl((int)pk10, srcB);
        const unsigned b11 = (unsigned)__shfl((int)pk11, srcB);
        const bool hi2 = (quad >= 2);
        const half8 pf = mk8(hi2 ? a10 : a00, hi2 ? a11 : a01,
                             hi2 ? b10 : b00, hi2 ? b11 : b01);

        // ---- O^T += K^T . P^T over this wave's d-half (swizzled A-frag reads) ----
        #pragma unroll
        for (int dt = 0; dt < 16; ++dt) {
            const int drow = dbase + dt * 16 + col;
            const int sw = (drow >> 3) & 3;
            half8 af = *(const half8*)&sKt[drow * TS + ((quad ^ sw) * 8)];
            acc[dt] = __builtin_amdgcn_mfma_f32_16x16x32_f16(af, pf, acc[dt], 0, 0, 0);
        }
    }

    // ---- epilogue: normalize and store this wave's d-half ----
    const float inv = 1.f / l_run;
    float* op = Og + ((size_t)batch * NQ + qrow) * DIM + dbase + quad * 4;
    #pragma unroll
    for (int dt = 0; dt < 16; ++dt) {
        floatx4 v = acc[dt] * inv;
        *(floatx4*)(op + dt * 16) = v;
    }
}

extern "C" void kernel_launch(void* const* d_in, const int* in_sizes, int n_in,
                              void* d_out, int out_size, void* d_ws, size_t ws_size,
                              hipStream_t stream) {
    (void)in_sizes; (void)n_in; (void)d_ws; (void)ws_size; (void)out_size;
    const float* Q = (const float*)d_in[0];
    const float* K = (const float*)d_in[1];
    float* O = (float*)d_out;
    dim3 grid(256), block(512);
    hipLaunchKernelGGL(attn_fa, grid, block, 0, stream, Q, K, O);
}

// Round 4
// 272.259 us; speedup vs baseline: 1.3153x; 1.2610x over previous
//
#include <hip/hip_runtime.h>

typedef _Float16 half8  __attribute__((ext_vector_type(8)));
typedef __fp16   fp16x2 __attribute__((ext_vector_type(2)));
typedef float    floatx4 __attribute__((ext_vector_type(4)));

#define LOG2E 1.44269504088896340736f

#define NQ  2048
#define NK  2048
#define DIM 512
#define KT  32

// sKr: 32 k-rows x 512d f16, row stride 512 (no pad). d-group (8 f16 = 16B)
//      XOR-swizzled: g' = g ^ key(k), key(k) = ((k&3)<<1)|((k>>2)&1).
//      Verified conflict-free (8 lanes/bank-group) for b128 writes and reads.
// sKt: K^T pair-slot layout. dp = d>>1, slot = ((dp&3)<<6)|(dp>>2), 72 f16/slot
//      = [kgroup g' (16B)][d&1 (16B... within 32B)] with g' = g ^ (dp&3).
//      slot stride 144B = 9 x 16B (odd) -> verified conflict-free b128 W/R.
// sSx: partial-S exchange between d-half partner waves, lane-sequential 16B.

__global__ __launch_bounds__(256, 2)
void attn_fa(const float* __restrict__ Qg, const float* __restrict__ Kg,
             float* __restrict__ Og)
{
    __shared__ __align__(16) _Float16 sKr[KT * 512];       // 32768 B
    __shared__ __align__(16) _Float16 sKt[256 * 72];       // 36864 B
    __shared__ __align__(16) float    sSx[4 * 2 * 64 * 4]; //  8192 B  => 77824 B total

    const int tid  = threadIdx.x;
    const int lane = tid & 63;
    const int wave = tid >> 6;      // 0..3
    const int quad = lane >> 4;
    const int col  = lane & 15;
    const int wq   = wave & 1;      // q-strip (16 rows)
    const int wg   = wave >> 1;     // d-half
    const int dbase = wg * 256;

    const int batch = blockIdx.x & 7;     // batch -> XCD: K resident in one L2
    const int qtile = blockIdx.x >> 3;    // 0..63
    const int qrow  = qtile * 32 + wq * 16 + col;

    // ---- Q fragments (B-layout): Q[q=col][d = dbase + dc*32 + quad*8 + j] ----
    const float* qp = Qg + ((size_t)batch * NQ + qrow) * DIM + dbase + quad * 8;
    half8 qf[8];
    #pragma unroll
    for (int dc = 0; dc < 8; ++dc) {
        float4 f0 = *(const float4*)(qp + dc * 32);
        float4 f1 = *(const float4*)(qp + dc * 32 + 4);
        union { unsigned u[4]; half8 h; } t;
        t.u[0] = __builtin_bit_cast(unsigned, __builtin_amdgcn_cvt_pkrtz(f0.x, f0.y));
        t.u[1] = __builtin_bit_cast(unsigned, __builtin_amdgcn_cvt_pkrtz(f0.z, f0.w));
        t.u[2] = __builtin_bit_cast(unsigned, __builtin_amdgcn_cvt_pkrtz(f1.x, f1.y));
        t.u[3] = __builtin_bit_cast(unsigned, __builtin_amdgcn_cvt_pkrtz(f1.z, f1.w));
        qf[dc] = t.h;
    }

    // O^T accumulator: acc[dt] holds O[q=col][d = dbase + dt*16 + quad*4 + r]
    floatx4 acc[16];
    #pragma unroll
    for (int i = 0; i < 16; ++i) acc[i] = (floatx4){0.f, 0.f, 0.f, 0.f};

    float m_run = -INFINITY;
    float l_run = 0.f;

    const int keyc = ((col & 3) << 1) | ((col >> 2) & 1);  // sKr read key (rows col & col+16 share)

    for (int kt = 0; kt < NK / KT; ++kt) {
        __syncthreads();
        // ---- stage K tile: thread = 8 k-rows (wave*8+kk) x 8 d (lane*8+dd) ----
        {
            const float* kp = Kg + ((size_t)batch * NK + kt * KT + wave * 8) * DIM + lane * 8;
            float rv[8][8];
            #pragma unroll
            for (int kk = 0; kk < 8; ++kk) {
                float4 f0 = *(const float4*)(kp + kk * DIM);
                float4 f1 = *(const float4*)(kp + kk * DIM + 4);
                rv[kk][0] = f0.x; rv[kk][1] = f0.y; rv[kk][2] = f0.z; rv[kk][3] = f0.w;
                rv[kk][4] = f1.x; rv[kk][5] = f1.y; rv[kk][6] = f1.z; rv[kk][7] = f1.w;
            }
            #pragma unroll
            for (int kk = 0; kk < 8; ++kk) {    // sKr row-major b128, swizzled
                const int row = wave * 8 + kk;
                const int key = ((row & 3) << 1) | ((row >> 2) & 1);
                uint4 w;
                w.x = __builtin_bit_cast(unsigned, __builtin_amdgcn_cvt_pkrtz(rv[kk][0], rv[kk][1]));
                w.y = __builtin_bit_cast(unsigned, __builtin_amdgcn_cvt_pkrtz(rv[kk][2], rv[kk][3]));
                w.z = __builtin_bit_cast(unsigned, __builtin_amdgcn_cvt_pkrtz(rv[kk][4], rv[kk][5]));
                w.w = __builtin_bit_cast(unsigned, __builtin_amdgcn_cvt_pkrtz(rv[kk][6], rv[kk][7]));
                *(uint4*)&sKr[row * 512 + ((lane ^ key) << 3)] = w;
            }
            #pragma unroll
            for (int dd = 0; dd < 8; ++dd) {    // sKt transposed b128 (8 k per d), slot layout
                const int pp = dd >> 1;
                const int b  = dd & 1;
                const int slot = (pp << 6) | lane;
                uint4 w;
                w.x = __builtin_bit_cast(unsigned, __builtin_amdgcn_cvt_pkrtz(rv[0][dd], rv[1][dd]));
                w.y = __builtin_bit_cast(unsigned, __builtin_amdgcn_cvt_pkrtz(rv[2][dd], rv[3][dd]));
                w.z = __builtin_bit_cast(unsigned, __builtin_amdgcn_cvt_pkrtz(rv[4][dd], rv[5][dd]));
                w.w = __builtin_bit_cast(unsigned, __builtin_amdgcn_cvt_pkrtz(rv[6][dd], rv[7][dd]));
                *(uint4*)&sKt[slot * 72 + ((wave ^ pp) << 4) + (b << 3)] = w;
            }
        }
        __syncthreads();

        // ---- partial S^T over this wave's d-half ----
        floatx4 s0 = {0.f, 0.f, 0.f, 0.f}, s1 = {0.f, 0.f, 0.f, 0.f};
        #pragma unroll
        for (int dc = 0; dc < 8; ++dc) {
            const int g = wg * 32 + dc * 4 + quad;
            const int off = ((g ^ keyc) << 3);
            half8 a0 = *(const half8*)&sKr[col * 512 + off];
            half8 a1 = *(const half8*)&sKr[(col + 16) * 512 + off];
            s0 = __builtin_amdgcn_mfma_f32_16x16x32_f16(a0, qf[dc], s0, 0, 0, 0);
            s1 = __builtin_amdgcn_mfma_f32_16x16x32_f16(a1, qf[dc], s1, 0, 0, 0);
        }

        // ---- combine d-half partials with partner wave (wave ^ 2) ----
        *(floatx4*)&sSx[((wave * 2 + 0) * 64 + lane) * 4] = s0;
        *(floatx4*)&sSx[((wave * 2 + 1) * 64 + lane) * 4] = s1;
        __syncthreads();
        {
            const int pw = wave ^ 2;
            s0 += *(const floatx4*)&sSx[((pw * 2 + 0) * 64 + lane) * 4];
            s1 += *(const floatx4*)&sSx[((pw * 2 + 1) * 64 + lane) * 4];
        }

        // ---- online softmax (q = col lane-local; reduce across quads) ----
        float mloc = fmaxf(fmaxf(fmaxf(s0[0], s0[1]), fmaxf(s0[2], s0[3])),
                           fmaxf(fmaxf(s1[0], s1[1]), fmaxf(s1[2], s1[3])));
        mloc = fmaxf(mloc, __shfl_xor(mloc, 16));
        mloc = fmaxf(mloc, __shfl_xor(mloc, 32));
        const float m_new = fmaxf(m_run, mloc);
        const float alpha = exp2f((m_run - m_new) * LOG2E);
        const float p0 = exp2f((s0[0] - m_new) * LOG2E);
        const float p1 = exp2f((s0[1] - m_new) * LOG2E);
        const float p2 = exp2f((s0[2] - m_new) * LOG2E);
        const float p3 = exp2f((s0[3] - m_new) * LOG2E);
        const float p4 = exp2f((s1[0] - m_new) * LOG2E);
        const float p5 = exp2f((s1[1] - m_new) * LOG2E);
        const float p6 = exp2f((s1[2] - m_new) * LOG2E);
        const float p7 = exp2f((s1[3] - m_new) * LOG2E);
        float sloc = ((p0 + p1) + (p2 + p3)) + ((p4 + p5) + (p6 + p7));
        sloc += __shfl_xor(sloc, 16);
        sloc += __shfl_xor(sloc, 32);
        l_run = l_run * alpha + sloc;
        m_run = m_new;

        #pragma unroll
        for (int i = 0; i < 16; ++i) acc[i] *= alpha;

        // ---- P fragment: B[k = quad*8 + j][q = col] via cross-quad shuffles ----
        const unsigned pk00 = __builtin_bit_cast(unsigned, __builtin_amdgcn_cvt_pkrtz(p0, p1));
        const unsigned pk01 = __builtin_bit_cast(unsigned, __builtin_amdgcn_cvt_pkrtz(p2, p3));
        const unsigned pk10 = __builtin_bit_cast(unsigned, __builtin_amdgcn_cvt_pkrtz(p4, p5));
        const unsigned pk11 = __builtin_bit_cast(unsigned, __builtin_amdgcn_cvt_pkrtz(p6, p7));
        const int srcA = col + ((quad & 1) << 5);
        const int srcB = srcA + 16;
        const unsigned a00 = (unsigned)__shfl((int)pk00, srcA);
        const unsigned a01 = (unsigned)__shfl((int)pk01, srcA);
        const unsigned a10 = (unsigned)__shfl((int)pk10, srcA);
        const unsigned a11 = (unsigned)__shfl((int)pk11, srcA);
        const unsigned b00 = (unsigned)__shfl((int)pk00, srcB);
        const unsigned b01 = (unsigned)__shfl((int)pk01, srcB);
        const unsigned b10 = (unsigned)__shfl((int)pk10, srcB);
        const unsigned b11 = (unsigned)__shfl((int)pk11, srcB);
        const bool hi2 = (quad >= 2);
        union { unsigned u[4]; half8 h; } pt;
        pt.u[0] = hi2 ? a10 : a00;
        pt.u[1] = hi2 ? a11 : a01;
        pt.u[2] = hi2 ? b10 : b00;
        pt.u[3] = hi2 ? b11 : b01;
        const half8 pf = pt.h;

        // ---- O^T += K^T . P^T over this wave's d-half (slot-layout A reads) ----
        #pragma unroll
        for (int dt = 0; dt < 16; ++dt) {
            const int drow = dbase + dt * 16 + col;
            const int dp = drow >> 1;
            const int off = (((dp & 3) << 6) | (dp >> 2)) * 72
                          + ((quad ^ (dp & 3)) << 4) + ((drow & 1) << 3);
            half8 af = *(const half8*)&sKt[off];
            acc[dt] = __builtin_amdgcn_mfma_f32_16x16x32_f16(af, pf, acc[dt], 0, 0, 0);
        }
    }

    // ---- epilogue: normalize and store this wave's d-half ----
    const float inv = 1.f / l_run;
    float* op = Og + ((size_t)batch * NQ + qrow) * DIM + dbase + quad * 4;
    #pragma unroll
    for (int dt = 0; dt < 16; ++dt) {
        floatx4 v = acc[dt] * inv;
        *(floatx4*)(op + dt * 16) = v;
    }
}

extern "C" void kernel_launch(void* const* d_in, const int* in_sizes, int n_in,
                              void* d_out, int out_size, void* d_ws, size_t ws_size,
                              hipStream_t stream) {
    (void)in_sizes; (void)n_in; (void)d_ws; (void)ws_size; (void)out_size;
    const float* Q = (const float*)d_in[0];
    const float* K = (const float*)d_in[1];
    float* O = (float*)d_out;
    dim3 grid(512), block(256);
    hipLaunchKernelGGL(attn_fa, grid, block, 0, stream, Q, K, O);
}